// Round 2
// baseline (405.797 us; speedup 1.0000x reference)
//
#include <hip/hip_runtime.h>

// Problem constants (reference: BATCH=64, NUM_SPEC=8, VOCAB=128000)
constexpr int BATCH    = 64;
constexpr int NUM_SPEC = 8;
constexpr int VOCAB    = 128000;
constexpr int ROWS     = BATCH * NUM_SPEC;   // 512 argmax rows
constexpr int NVEC     = VOCAB / 4;          // 32000 float4 per row
constexpr int T1       = 1024;               // threads per argmax block (16 waves)

// Per-row argmax over vocab, first-index tie-break (matches jnp.argmax).
// One 1024-thread block per row: 512 blocks -> 2 blocks/CU -> 32 waves/CU
// (full occupancy; __launch_bounds__(1024,8) caps VGPR<=64 so 8 waves/SIMD fit).
// 31.25 float4 strides/thread = 7 unrolled groups of 4 + 3 tail + 1 predicated.
// All indices visited in increasing order per thread, so '>' alone preserves
// the lowest index on exact float ties.
__global__ __launch_bounds__(T1, 8) void rs_argmax(const float* __restrict__ logits,
                                                   int* __restrict__ targets) {
    const int row = blockIdx.x;  // 0..511
    const int tid = threadIdx.x;
    const float4* __restrict__ rowp =
        reinterpret_cast<const float4*>(logits + (size_t)row * VOCAB);

    float best = -__builtin_inff();
    int   bidx = VOCAB;  // sentinel

    auto upd = [&](const float4 v, const int vecidx) {
        const int base = vecidx << 2;
        if (v.x > best) { best = v.x; bidx = base;     }
        if (v.y > best) { best = v.y; bidx = base + 1; }
        if (v.z > best) { best = v.z; bidx = base + 2; }
        if (v.w > best) { best = v.w; bidx = base + 3; }
    };

    // 7 groups x 4 strides: covers vec indices [tid + k*1024, k=0..27] < 28672+tid
    #pragma unroll
    for (int j = 0; j < 7; ++j) {
        const int i = tid + j * 4096;
        const float4 v0 = rowp[i];
        const float4 v1 = rowp[i + 1024];
        const float4 v2 = rowp[i + 2048];
        const float4 v3 = rowp[i + 3072];
        upd(v0, i);
        upd(v1, i + 1024);
        upd(v2, i + 2048);
        upd(v3, i + 3072);
    }
    // Tail: strides k=28,29,30 are full; k=31 only for tid<256 (wave-uniform:
    // tid<256 is exactly waves 0..3, no intra-wave divergence).
    {
        const int i = tid + 28672;
        const float4 v0 = rowp[i];
        const float4 v1 = rowp[i + 1024];
        const float4 v2 = rowp[i + 2048];
        const bool has4 = (tid < 256);  // tid+31744 < 32000
        float4 v3;
        if (has4) v3 = rowp[i + 3072];
        upd(v0, i);
        upd(v1, i + 1024);
        upd(v2, i + 2048);
        if (has4) upd(v3, i + 3072);
    }

    // 64-lane wave reduction, lowest-index tie-break.
    #pragma unroll
    for (int off = 32; off > 0; off >>= 1) {
        const float ov = __shfl_down(best, off, 64);
        const int   oi = __shfl_down(bidx, off, 64);
        if (ov > best || (ov == best && oi < bidx)) { best = ov; bidx = oi; }
    }

    __shared__ float sval[T1 / 64];
    __shared__ int   sidx[T1 / 64];
    const int lane = tid & 63;
    const int wave = tid >> 6;
    if (lane == 0) { sval[wave] = best; sidx[wave] = bidx; }
    __syncthreads();

    if (tid == 0) {
        best = sval[0]; bidx = sidx[0];
        #pragma unroll
        for (int w = 1; w < T1 / 64; ++w) {
            if (sval[w] > best || (sval[w] == best && sidx[w] < bidx)) {
                best = sval[w]; bidx = sidx[w];
            }
        }
        targets[row] = bidx;
    }
}

// Per-batch rejection-sampling logic. One thread per batch row.
// Output layout (int32, concatenated flat in return order):
//   [0,   576)  output_token_ids [64,9]
//   [576, 640)  num_rejected_tokens [64]
//   [640, 704)  last_token_ids [64]
__global__ __launch_bounds__(64) void rs_finalize(const int* __restrict__ targets,
                                                  const int* __restrict__ draft,
                                                  const int* __restrict__ bonus,
                                                  int* __restrict__ out) {
    const int b = threadIdx.x;
    if (b >= BATCH) return;

    int tgt[NUM_SPEC];
    int L = 0;            // matched-prefix length
    bool prefix = true;
    #pragma unroll
    for (int s = 0; s < NUM_SPEC; ++s) {
        tgt[s] = targets[b * NUM_SPEC + s];
        const bool m = (draft[b * NUM_SPEC + s] == tgt[s]);
        prefix = prefix && m;
        if (prefix) ++L;
    }

    const bool all_acc = (L == NUM_SPEC);
    const int keep_cnt = all_acc ? NUM_SPEC : (L + 1);

    int* __restrict__ out_tok = out + b * (NUM_SPEC + 1);
    #pragma unroll
    for (int s = 0; s < NUM_SPEC; ++s) {
        out_tok[s] = (s < keep_cnt) ? tgt[s] : -1;
    }
    const int bonus_tok = bonus[b];
    out_tok[NUM_SPEC] = all_acc ? bonus_tok : -1;

    out[BATCH * (NUM_SPEC + 1) + b] = NUM_SPEC - L;                // num_rejected
    out[BATCH * (NUM_SPEC + 1) + BATCH + b] = all_acc ? bonus_tok  // last_token
                                                      : tgt[L];
}

extern "C" void kernel_launch(void* const* d_in, const int* in_sizes, int n_in,
                              void* d_out, int out_size, void* d_ws, size_t ws_size,
                              hipStream_t stream) {
    const float* logits = (const float*)d_in[0];  // [64, 8, 128000] fp32
    const int*   draft  = (const int*)d_in[1];    // [64, 8] int32
    const int*   bonus  = (const int*)d_in[2];    // [64, 1] int32
    int* out = (int*)d_out;                       // 704 int32
    int* targets = (int*)d_ws;                    // 512 int32 scratch

    rs_argmax<<<ROWS, T1, 0, stream>>>(logits, targets);
    rs_finalize<<<1, 64, 0, stream>>>(targets, draft, bonus, out);
}

// Round 4
// 384.270 us; speedup vs baseline: 1.0560x; 1.0560x over previous
//
#include <hip/hip_runtime.h>

// Problem constants (reference: BATCH=64, NUM_SPEC=8, VOCAB=128000)
constexpr int BATCH    = 64;
constexpr int NUM_SPEC = 8;
constexpr int VOCAB    = 128000;
constexpr int ROWS     = BATCH * NUM_SPEC;   // 512 argmax rows
constexpr int NVEC     = VOCAB / 4;          // 32000 float4 per row
constexpr int T1       = 1024;               // threads per argmax block (16 waves)

// Native Clang vector type: __builtin_nontemporal_load requires a pointer to
// scalar/native-vector (HIP_vector_type<float,4> is a struct and is rejected).
typedef float vfloat4 __attribute__((ext_vector_type(4)));

// Per-row argmax over vocab, first-index tie-break (matches jnp.argmax).
// One 1024-thread block per row: 512 blocks -> 2 blocks/CU -> 32 waves/CU.
//
// KEY: loads are NON-TEMPORAL. The harness poisons a ~1 GB d_ws with 0xAA
// before every timed replay, leaving L2/L3 full of dirty lines; a normally-
// allocating streaming read forces ~178 MB of writeback evictions during this
// kernel (R2's WRITE_SIZE on rs_argmax) and drops effective read BW to
// 1.67 TB/s. NT loads skip cache allocation (still coherent) -> no eviction
// storm -> pure streaming read.
__global__ __launch_bounds__(T1, 8) void rs_argmax(const float* __restrict__ logits,
                                                   int* __restrict__ targets) {
    const int row = blockIdx.x;  // 0..511
    const int tid = threadIdx.x;
    const vfloat4* __restrict__ rowp =
        reinterpret_cast<const vfloat4*>(logits + (size_t)row * VOCAB);

    float best = -__builtin_inff();
    int   bidx = VOCAB;  // sentinel

    auto upd = [&](const vfloat4 v, const int vecidx) {
        const int base = vecidx << 2;
        if (v.x > best) { best = v.x; bidx = base;     }
        if (v.y > best) { best = v.y; bidx = base + 1; }
        if (v.z > best) { best = v.z; bidx = base + 2; }
        if (v.w > best) { best = v.w; bidx = base + 3; }
    };

    // 7 groups x 4 strides: vec indices tid + k*1024, k = 0..27.
    // Indices per thread strictly increase, so '>' keeps lowest index on ties.
    #pragma unroll
    for (int j = 0; j < 7; ++j) {
        const int i = tid + j * 4096;
        const vfloat4 v0 = __builtin_nontemporal_load(rowp + i);
        const vfloat4 v1 = __builtin_nontemporal_load(rowp + i + 1024);
        const vfloat4 v2 = __builtin_nontemporal_load(rowp + i + 2048);
        const vfloat4 v3 = __builtin_nontemporal_load(rowp + i + 3072);
        upd(v0, i);
        upd(v1, i + 1024);
        upd(v2, i + 2048);
        upd(v3, i + 3072);
    }
    // Tail: k = 28,29,30 full; k = 31 only for tid < 256 (waves 0..3, no
    // intra-wave divergence).
    {
        const int i = tid + 28672;
        const vfloat4 v0 = __builtin_nontemporal_load(rowp + i);
        const vfloat4 v1 = __builtin_nontemporal_load(rowp + i + 1024);
        const vfloat4 v2 = __builtin_nontemporal_load(rowp + i + 2048);
        const bool has4 = (tid < 256);  // tid + 31744 < 32000
        vfloat4 v3 = {0.f, 0.f, 0.f, 0.f};
        if (has4) v3 = __builtin_nontemporal_load(rowp + i + 3072);
        upd(v0, i);
        upd(v1, i + 1024);
        upd(v2, i + 2048);
        if (has4) upd(v3, i + 3072);
    }

    // 64-lane wave reduction, lowest-index tie-break.
    #pragma unroll
    for (int off = 32; off > 0; off >>= 1) {
        const float ov = __shfl_down(best, off, 64);
        const int   oi = __shfl_down(bidx, off, 64);
        if (ov > best || (ov == best && oi < bidx)) { best = ov; bidx = oi; }
    }

    __shared__ float sval[T1 / 64];
    __shared__ int   sidx[T1 / 64];
    const int lane = tid & 63;
    const int wave = tid >> 6;
    if (lane == 0) { sval[wave] = best; sidx[wave] = bidx; }
    __syncthreads();

    if (tid == 0) {
        best = sval[0]; bidx = sidx[0];
        #pragma unroll
        for (int w = 1; w < T1 / 64; ++w) {
            if (sval[w] > best || (sval[w] == best && sidx[w] < bidx)) {
                best = sval[w]; bidx = sidx[w];
            }
        }
        targets[row] = bidx;
    }
}

// Per-batch rejection-sampling logic. One thread per batch row.
// Output layout (int32, concatenated flat in return order):
//   [0,   576)  output_token_ids [64,9]
//   [576, 640)  num_rejected_tokens [64]
//   [640, 704)  last_token_ids [64]
__global__ __launch_bounds__(64) void rs_finalize(const int* __restrict__ targets,
                                                  const int* __restrict__ draft,
                                                  const int* __restrict__ bonus,
                                                  int* __restrict__ out) {
    const int b = threadIdx.x;
    if (b >= BATCH) return;

    int tgt[NUM_SPEC];
    int L = 0;            // matched-prefix length
    bool prefix = true;
    #pragma unroll
    for (int s = 0; s < NUM_SPEC; ++s) {
        tgt[s] = targets[b * NUM_SPEC + s];
        const bool m = (draft[b * NUM_SPEC + s] == tgt[s]);
        prefix = prefix && m;
        if (prefix) ++L;
    }

    const bool all_acc = (L == NUM_SPEC);
    const int keep_cnt = all_acc ? NUM_SPEC : (L + 1);

    int* __restrict__ out_tok = out + b * (NUM_SPEC + 1);
    #pragma unroll
    for (int s = 0; s < NUM_SPEC; ++s) {
        out_tok[s] = (s < keep_cnt) ? tgt[s] : -1;
    }
    const int bonus_tok = bonus[b];
    out_tok[NUM_SPEC] = all_acc ? bonus_tok : -1;

    out[BATCH * (NUM_SPEC + 1) + b] = NUM_SPEC - L;                // num_rejected
    out[BATCH * (NUM_SPEC + 1) + BATCH + b] = all_acc ? bonus_tok  // last_token
                                                      : tgt[L];
}

extern "C" void kernel_launch(void* const* d_in, const int* in_sizes, int n_in,
                              void* d_out, int out_size, void* d_ws, size_t ws_size,
                              hipStream_t stream) {
    const float* logits = (const float*)d_in[0];  // [64, 8, 128000] fp32
    const int*   draft  = (const int*)d_in[1];    // [64, 8] int32
    const int*   bonus  = (const int*)d_in[2];    // [64, 1] int32
    int* out = (int*)d_out;                       // 704 int32
    int* targets = (int*)d_ws;                    // 512 int32 scratch

    rs_argmax<<<ROWS, T1, 0, stream>>>(logits, targets);
    rs_finalize<<<1, 64, 0, stream>>>(targets, draft, bonus, out);
}

// Round 5
// 326.488 us; speedup vs baseline: 1.2429x; 1.1770x over previous
//
#include <hip/hip_runtime.h>

// Problem constants (reference: BATCH=64, NUM_SPEC=8, VOCAB=128000)
constexpr int BATCH    = 64;
constexpr int NUM_SPEC = 8;
constexpr int VOCAB    = 128000;
constexpr int ROWS     = BATCH * NUM_SPEC;   // 512 argmax rows
constexpr int NVEC     = VOCAB / 4;          // 32000 float4 per row
constexpr int T1       = 1024;               // threads per argmax block (16 waves)

// Native Clang vector type (maps to a 4-VGPR tuple).
typedef float vfloat4 __attribute__((ext_vector_type(4)));

// Fully cache-bypassing streaming load: sc0 sc1 nt = system-scope,
// non-temporal. R2 showed a 178 MB dirty-writeback storm (WRITE_SIZE on a
// kernel that writes 2 KB) from the harness's 1 GB 0xAA ws-poison leaving the
// LLC full of dirty lines; plain nt (R4) only partially helped (~157->~135us).
// Bypassing allocation entirely means our 262 MB read stream forces no
// evictions at all. Memory-side LLC stays coherent for bypassing reads.
__device__ __forceinline__ void nt_load(vfloat4& dst, const vfloat4* addr) {
    asm volatile("global_load_dwordx4 %0, %1, off sc0 sc1 nt"
                 : "=v"(dst) : "v"(addr));
}
// Explicit drain: asm loads are invisible to the compiler's vmcnt tracking,
// so tie the loaded values to a s_waitcnt before consumption.
__device__ __forceinline__ void wait4(vfloat4& a, vfloat4& b, vfloat4& c, vfloat4& d) {
    asm volatile("s_waitcnt vmcnt(0)"
                 : "+v"(a), "+v"(b), "+v"(c), "+v"(d));
}

// Per-row argmax over vocab, first-index tie-break (matches jnp.argmax).
// One 1024-thread block per row: 512 blocks -> 2 blocks/CU -> 32 waves/CU.
// Latency note: 4 loads in flight/wave x 32 waves/CU >> Little's-law need
// (~9.2 KB/CU at 24.6 GB/s/CU), so per-group vmcnt(0) drains are safe.
__global__ __launch_bounds__(T1, 8) void rs_argmax(const float* __restrict__ logits,
                                                   int* __restrict__ targets) {
    const int row = blockIdx.x;  // 0..511
    const int tid = threadIdx.x;
    const vfloat4* __restrict__ rowp =
        reinterpret_cast<const vfloat4*>(logits + (size_t)row * VOCAB);

    float best = -__builtin_inff();
    int   bidx = VOCAB;  // sentinel

    auto upd = [&](const vfloat4 v, const int vecidx) {
        const int base = vecidx << 2;
        if (v.x > best) { best = v.x; bidx = base;     }
        if (v.y > best) { best = v.y; bidx = base + 1; }
        if (v.z > best) { best = v.z; bidx = base + 2; }
        if (v.w > best) { best = v.w; bidx = base + 3; }
    };

    // 7 groups x 4 strides: vec indices tid + k*1024, k = 0..27.
    // Per-thread indices strictly increase, so '>' keeps lowest index on ties.
    #pragma unroll
    for (int j = 0; j < 7; ++j) {
        const int i = tid + j * 4096;
        vfloat4 v0, v1, v2, v3;
        nt_load(v0, rowp + i);
        nt_load(v1, rowp + i + 1024);
        nt_load(v2, rowp + i + 2048);
        nt_load(v3, rowp + i + 3072);
        wait4(v0, v1, v2, v3);
        upd(v0, i);
        upd(v1, i + 1024);
        upd(v2, i + 2048);
        upd(v3, i + 3072);
    }
    // Tail: k = 28,29,30 full; k = 31 exists only for tid < 256. Keep the
    // load uniform (clamp the address back in-bounds for tid >= 256 — row 511
    // would otherwise read past the allocation) and predicate the update.
    // Even unguarded it would be value-safe (duplicate of k=28, already
    // folded), but the guard keeps intent explicit.
    {
        const int i = tid + 28672;
        const bool has4 = (tid < 256);  // tid + 31744 < 32000
        const vfloat4* p3 = has4 ? (rowp + i + 3072) : (rowp + i);
        vfloat4 v0, v1, v2, v3;
        nt_load(v0, rowp + i);
        nt_load(v1, rowp + i + 1024);
        nt_load(v2, rowp + i + 2048);
        nt_load(v3, p3);
        wait4(v0, v1, v2, v3);
        upd(v0, i);
        upd(v1, i + 1024);
        upd(v2, i + 2048);
        if (has4) upd(v3, i + 3072);
    }

    // 64-lane wave reduction, lowest-index tie-break.
    #pragma unroll
    for (int off = 32; off > 0; off >>= 1) {
        const float ov = __shfl_down(best, off, 64);
        const int   oi = __shfl_down(bidx, off, 64);
        if (ov > best || (ov == best && oi < bidx)) { best = ov; bidx = oi; }
    }

    __shared__ float sval[T1 / 64];
    __shared__ int   sidx[T1 / 64];
    const int lane = tid & 63;
    const int wave = tid >> 6;
    if (lane == 0) { sval[wave] = best; sidx[wave] = bidx; }
    __syncthreads();

    if (tid == 0) {
        best = sval[0]; bidx = sidx[0];
        #pragma unroll
        for (int w = 1; w < T1 / 64; ++w) {
            if (sval[w] > best || (sval[w] == best && sidx[w] < bidx)) {
                best = sval[w]; bidx = sidx[w];
            }
        }
        targets[row] = bidx;
    }
}

// Per-batch rejection-sampling logic. One thread per batch row.
// Output layout (int32, concatenated flat in return order):
//   [0,   576)  output_token_ids [64,9]
//   [576, 640)  num_rejected_tokens [64]
//   [640, 704)  last_token_ids [64]
__global__ __launch_bounds__(64) void rs_finalize(const int* __restrict__ targets,
                                                  const int* __restrict__ draft,
                                                  const int* __restrict__ bonus,
                                                  int* __restrict__ out) {
    const int b = threadIdx.x;
    if (b >= BATCH) return;

    int tgt[NUM_SPEC];
    int L = 0;            // matched-prefix length
    bool prefix = true;
    #pragma unroll
    for (int s = 0; s < NUM_SPEC; ++s) {
        tgt[s] = targets[b * NUM_SPEC + s];
        const bool m = (draft[b * NUM_SPEC + s] == tgt[s]);
        prefix = prefix && m;
        if (prefix) ++L;
    }

    const bool all_acc = (L == NUM_SPEC);
    const int keep_cnt = all_acc ? NUM_SPEC : (L + 1);

    int* __restrict__ out_tok = out + b * (NUM_SPEC + 1);
    #pragma unroll
    for (int s = 0; s < NUM_SPEC; ++s) {
        out_tok[s] = (s < keep_cnt) ? tgt[s] : -1;
    }
    const int bonus_tok = bonus[b];
    out_tok[NUM_SPEC] = all_acc ? bonus_tok : -1;

    out[BATCH * (NUM_SPEC + 1) + b] = NUM_SPEC - L;                // num_rejected
    out[BATCH * (NUM_SPEC + 1) + BATCH + b] = all_acc ? bonus_tok  // last_token
                                                      : tgt[L];
}

extern "C" void kernel_launch(void* const* d_in, const int* in_sizes, int n_in,
                              void* d_out, int out_size, void* d_ws, size_t ws_size,
                              hipStream_t stream) {
    const float* logits = (const float*)d_in[0];  // [64, 8, 128000] fp32
    const int*   draft  = (const int*)d_in[1];    // [64, 8] int32
    const int*   bonus  = (const int*)d_in[2];    // [64, 1] int32
    int* out = (int*)d_out;                       // 704 int32
    int* targets = (int*)d_ws;                    // 512 int32 scratch

    rs_argmax<<<ROWS, T1, 0, stream>>>(logits, targets);
    rs_finalize<<<1, 64, 0, stream>>>(targets, draft, bonus, out);
}